// Round 9
// baseline (648.189 us; speedup 1.0000x reference)
//
#include <hip/hip_runtime.h>
#include <hip/hip_bf16.h>

#define Q_TOT 1024
#define T_TOT 256
#define NPTS  100
#define KD    300
#define EPSV  1e-6f

// d_ws layout (floats):
//   [0, 256*1216)           : per-target ext buffers: t*1216 + [0,600) fwd_ext,
//                             t*1216 + 608 + [0,600) bwd_ext
//   [WS_PT, WS_PT+75*1024*4): preds transposed: predT[kc][q] as float4
#define WS_PT (T_TOT*1216)

// ---------------------------------------------------------------------------
// Prep A: doubled fwd/bwd target buffers (read by MAIN via uniform s_loads).
// ---------------------------------------------------------------------------
__global__ void prep_tgt_ext(const float* __restrict__ tgt, float* __restrict__ ws)
{
    const int t = blockIdx.x;
    const float* tg = tgt + t*KD;
    float* wF = ws + t*1216;
    float* wR = wF + 608;
    for (int x = threadIdx.x; x < 600; x += blockDim.x) {
        int m = (x >= 300) ? (x-300) : x;
        int jj = m / 3;
        int c3 = m - jj*3;
        wF[x] = tg[m];
        wR[x] = tg[(NPTS-1-jj)*3 + c3];
    }
}

// ---------------------------------------------------------------------------
// Prep B: transpose preds to [kc][q] float4 (lane-contiguous coalesced loads).
// ---------------------------------------------------------------------------
__global__ void prep_predT(const float4* __restrict__ preds4, float4* __restrict__ pT)
{
    int i = blockIdx.x * blockDim.x + threadIdx.x;   // i = kc*1024 + q
    if (i >= 75*Q_TOT) return;
    int kc = i >> 10;
    int q  = i & 1023;
    pT[i] = preds4[q*75 + kc];
}

// ---------------------------------------------------------------------------
// One pass: NU shifted dot-products for FOUR TARGETS x one query per lane.
// Targets come from wave-uniform scalar loads (s_load/K$, free SGPR operand in
// v_fma); pred is ONE float4 per kc per lane.  52 accumulators per pred load
// cuts the L2 pred re-read traffic 4x vs R7 (the measured bottleneck).
// ---------------------------------------------------------------------------
template<int ABASE, int NU, bool P2>
__device__ __forceinline__ void dot_pass4t(
    const float* __restrict__ t0, const float* __restrict__ t1,
    const float* __restrict__ t2, const float* __restrict__ t3,
    const float4* __restrict__ pT, float (&acc)[4][NU], float& p2)
{
    #pragma unroll
    for (int tt = 0; tt < 4; ++tt)
        #pragma unroll
        for (int u = 0; u < NU; ++u) acc[tt][u] = 0.f;

    float4 pc = pT[0];
    #pragma clang loop unroll(disable)
    for (int kc = 0; kc < 75; ++kc) {
        const int kn = (kc+1 < 75) ? (kc+1) : 74;
        float4 pn = pT[kn*1024];               // 1-deep prefetch (4 VGPRs)
        if (P2)
            p2 = fmaf(pc.x,pc.x, fmaf(pc.y,pc.y, fmaf(pc.z,pc.z, fmaf(pc.w,pc.w, p2))));
        const float* tws[4] = {t0, t1, t2, t3};
        #pragma unroll
        for (int tt = 0; tt < 4; ++tt) {
            const float* twk = tws[tt] + 4*kc;     // uniform, +16B/iter
            #pragma unroll
            for (int u = 0; u < NU; ++u) {
                const int off = 300 - 3*(ABASE + u);   // compile-time
                float a0 = twk[off+0], a1 = twk[off+1];
                float a2 = twk[off+2], a3 = twk[off+3];
                acc[tt][u] = fmaf(a0,pc.x, fmaf(a1,pc.y,
                              fmaf(a2,pc.z, fmaf(a3,pc.w, acc[tt][u]))));
            }
        }
        pc = pn;
    }
}

template<int NU>
__device__ __forceinline__ void fold4t(const float (&acc)[4][NU], const float (&s2)[4],
                                       int vbase, float (&dmin)[4], int (&imin)[4])
{
    #pragma unroll
    for (int tt = 0; tt < 4; ++tt)
        #pragma unroll
        for (int u = 0; u < NU; ++u) {
            float d2 = fmaxf(fmaf(-2.f, acc[tt][u], s2[tt]), 0.f) * 0.01f;
            if (d2 < dmin[tt]) { dmin[tt] = d2; imin[tt] = vbase + u; } // strict < = first occ.
        }
}

// 25 variants (for all 4 targets), split 13+12 so the two passes' accumulator
// registers never coexist (R4's spill lesson).  Fold ascending in v.
template<int ABASE, int VBASE>
__device__ __forceinline__ void process4t(
    const float* __restrict__ t0, const float* __restrict__ t1,
    const float* __restrict__ t2, const float* __restrict__ t3,
    const float4* __restrict__ pT, const float (&v2)[4],
    float (&dmin)[4], int (&imin)[4], float (&df)[4])
{
    float p2 = 0.f;
    float s2[4];
    {
        float acc[4][13];
        dot_pass4t<ABASE, 13, true>(t0,t1,t2,t3, pT, acc, p2);
        #pragma unroll
        for (int tt = 0; tt < 4; ++tt) s2[tt] = v2[tt] + p2;
        if (VBASE == 0 || VBASE == 100) {       // d2 at v=0 (fwd) / v=100 (bwd)
            #pragma unroll
            for (int tt = 0; tt < 4; ++tt)
                df[tt] = fmaxf(fmaf(-2.f, acc[tt][0], s2[tt]), 0.f) * 0.01f;
        }
        fold4t<13>(acc, s2, VBASE, dmin, imin);
    }
    {
        float acc[4][12];
        dot_pass4t<ABASE+13, 12, false>(t0,t1,t2,t3, pT, acc, p2);
        fold4t<12>(acc, s2, VBASE+13, dmin, imin);
    }
}

// ---------------------------------------------------------------------------
// One block = 4 targets x 64 queries.  512 threads = 8 variant-group waves x
// 64 lanes; each thread: 4 targets x 25 variants x 1 query x 300-MAC dots.
// v = 25*vg + u ascending across waves -> first-occurrence argmin holds.
// ---------------------------------------------------------------------------
__global__ __launch_bounds__(512, 2) void matcher_main(
    const float* __restrict__ ws,      // prep output (tgt ext + predT)
    const float* __restrict__ plog,    // [1024][2]
    const float* __restrict__ ptyp,    // [1024][4]
    const float* __restrict__ clog,    // [1024][2]
    const int*   __restrict__ labels,  // [256]
    const int*   __restrict__ iscl,    // [256]
    const float* __restrict__ clw,     // [256]
    float* __restrict__ out)           // [2][1024][256] flat fp32
{
    __shared__ float red_min[8][256];  // [vg][tt*64+q]
    __shared__ int   red_idx[8][256];
    __shared__ float red_open[2][256];

    const int tg0  = blockIdx.x * 4;    // 4 targets per block
    const int qt   = blockIdx.y;        // 0..15, 64-query tile
    const int tid  = threadIdx.x;
    const int lane = tid & 63;
    const int vg   = tid >> 6;          // 0..7, uniform per wave

    const float* twF0 = ws + (tg0+0)*1216;  const float* twR0 = twF0 + 608;
    const float* twF1 = ws + (tg0+1)*1216;  const float* twR1 = twF1 + 608;
    const float* twF2 = ws + (tg0+2)*1216;  const float* twR2 = twF2 + 608;
    const float* twF3 = ws + (tg0+3)*1216;  const float* twR3 = twF3 + 608;
    const float4* pT = reinterpret_cast<const float4*>(ws + WS_PT) + (qt*64 + lane);

    // v2 per target: same fmaf chain/order as R7 (bit-identical results)
    float v2[4];
    {
        const float* tws[4] = {twF0, twF1, twF2, twF3};
        #pragma unroll
        for (int tt = 0; tt < 4; ++tt) {
            float acc = 0.f;
            const float* tw = tws[tt];
            #pragma clang loop unroll(disable)
            for (int i = 0; i < 75; ++i) {
                float a0 = tw[300+4*i+0], a1 = tw[300+4*i+1];
                float a2 = tw[300+4*i+2], a3 = tw[300+4*i+3];
                acc = fmaf(a0,a0, fmaf(a1,a1, fmaf(a2,a2, fmaf(a3,a3, acc))));
            }
            v2[tt] = acc;
        }
    }

    float dmin[4] = {3.4028235e38f,3.4028235e38f,3.4028235e38f,3.4028235e38f};
    int   imin[4] = {0,0,0,0};
    float df[4]   = {0.f,0.f,0.f,0.f};
    const int svg = __builtin_amdgcn_readfirstlane(vg);   // provably uniform
    switch (svg) {
        case 0:  process4t<0 ,  0>(twF0,twF1,twF2,twF3, pT, v2, dmin, imin, df); break;
        case 1:  process4t<25, 25>(twF0,twF1,twF2,twF3, pT, v2, dmin, imin, df); break;
        case 2:  process4t<50, 50>(twF0,twF1,twF2,twF3, pT, v2, dmin, imin, df); break;
        case 3:  process4t<75, 75>(twF0,twF1,twF2,twF3, pT, v2, dmin, imin, df); break;
        case 4:  process4t<0 ,100>(twR0,twR1,twR2,twR3, pT, v2, dmin, imin, df); break;
        case 5:  process4t<25,125>(twR0,twR1,twR2,twR3, pT, v2, dmin, imin, df); break;
        case 6:  process4t<50,150>(twR0,twR1,twR2,twR3, pT, v2, dmin, imin, df); break;
        default: process4t<75,175>(twR0,twR1,twR2,twR3, pT, v2, dmin, imin, df); break;
    }

    #pragma unroll
    for (int tt = 0; tt < 4; ++tt) {
        red_min[vg][tt*64 + lane] = dmin[tt];
        red_idx[vg][tt*64 + lane] = imin[tt];
    }
    if (vg == 0) {
        #pragma unroll
        for (int tt = 0; tt < 4; ++tt) red_open[0][tt*64 + lane] = df[tt]; // d2[v=0]
    }
    if (vg == 4) {
        #pragma unroll
        for (int tt = 0; tt < 4; ++tt) red_open[1][tt*64 + lane] = df[tt]; // d2[v=100]
    }
    __syncthreads();

    if (tid < 256) {
        const int tt = tid >> 6;              // 0..3 target-local
        const int t  = tg0 + tt;
        float mbest = red_min[0][tid]; int ibest = red_idx[0][tid];
        #pragma unroll
        for (int g = 1; g < 8; ++g) {         // ascending v-groups, strict <
            float mg = red_min[g][tid];
            if (mg < mbest) { mbest = mg; ibest = red_idx[g][tid]; }
        }
        int mapped = (ibest <= NPTS-1) ? ibest : (2*NPTS-1 - ibest);
        float od   = fminf(red_open[0][tid], red_open[1][tid]);
        int   isc  = iscl[t];                 // 0 or 1
        float geom = isc ? mbest : od;
        int   ido  = isc ? mapped : 0;
        geom *= clw[t];

        // Inline cost-class terms for query qg, target t.
        const int qg = qt*64 + (tid & 63);
        float t0 = ptyp[qg*4+0], t1 = ptyp[qg*4+1];
        float t2 = ptyp[qg*4+2], t3 = ptyp[qg*4+3];
        float mx = fmaxf(fmaxf(t0,t1), fmaxf(t2,t3));
        float e0 = expf(t0-mx), e1 = expf(t1-mx), e2 = expf(t2-mx), e3 = expf(t3-mx);
        float rs = 1.0f/(e0+e1+e2+e3);
        int lab  = labels[t];
        float el = (lab == 0) ? e0 : (lab == 1) ? e1 : (lab == 2) ? e2 : e3;
        float cost = -logf(el*rs + EPSV);
        float v0 = plog[qg*2+0], v1 = plog[qg*2+1];
        cost += -logf(1.0f/(1.0f + expf(v1-v0)) + EPSV);
        float c0 = clog[qg*2+0], c1 = clog[qg*2+1];
        float pc = isc ? (1.0f/(1.0f + expf(c0-c1))) : (1.0f/(1.0f + expf(c1-c0)));
        cost += -logf(pc + EPSV);

        float C = geom + cost;
        out[qg*T_TOT + t]               = C;
        out[Q_TOT*T_TOT + qg*T_TOT + t] = (float)ido;
    }
}

extern "C" void kernel_launch(void* const* d_in, const int* in_sizes, int n_in,
                              void* d_out, int out_size, void* d_ws, size_t ws_size,
                              hipStream_t stream)
{
    const float* preds  = (const float*)d_in[0];  // pred_curve_points (1,1024,100,3)
    const float* plog   = (const float*)d_in[1];  // pred_curve_logits (1,1024,2)
    const float* ptyp   = (const float*)d_in[2];  // pred_curve_type   (1,1024,4)
    const float* clog   = (const float*)d_in[3];  // closed_curve_logits (1,1024,2)
    const float* tgt    = (const float*)d_in[4];  // tgt_curve_points  (256,100,3)
    const int*   labels = (const int*)d_in[5];    // tgt_labels (256)
    const int*   iscl   = (const int*)d_in[6];    // tgt_is_closed (256)
    const float* clw    = (const float*)d_in[7];  // curve_length_weighting (256)
    float* out = (float*)d_out;
    float* ws  = (float*)d_ws;    // needs (256*1216 + 75*1024*4)*4 B = 2.47 MB

    prep_tgt_ext<<<dim3(T_TOT), dim3(256), 0, stream>>>(tgt, ws);
    prep_predT<<<dim3((75*Q_TOT + 255)/256), dim3(256), 0, stream>>>(
        (const float4*)preds, (float4*)(ws + WS_PT));
    matcher_main<<<dim3(T_TOT/4, Q_TOT/64), dim3(512), 0, stream>>>(
        ws, plog, ptyp, clog, labels, iscl, clw, out);
}

// Round 10
// 522.793 us; speedup vs baseline: 1.2399x; 1.2399x over previous
//
#include <hip/hip_runtime.h>
#include <hip/hip_fp16.h>

#define Q_TOT 1024
#define T_TOT 256
#define NPTS  100
#define KD    300
#define EPSV  1e-6f

#define EXTOFF 40            // zero pad in front (padded rows reach index -21)
#define EXTLEN 672           // f16 units per rotated copy (40 + 600 + tail pad)
#define KSTEPS 10            // 10 * 32 = 320 >= 300 (zero-padded K)
#define MT     14            // 7 M-tiles fwd (rows 0..111) + 7 bwd (rows 0..111)

typedef _Float16 f16;
typedef _Float16 f16x8 __attribute__((ext_vector_type(8)));
typedef float    f32x4 __attribute__((ext_vector_type(4)));
#define MFMA16 __builtin_amdgcn_mfma_f32_16x16x32_f16

// ws layout (floats):
//   [0,1024)       p2[q]  = sum(pred_q^2)      (fp32)
//   [1024,1280)    v2[t]  = sum(tgt_t^2)       (fp32)
//   [1280, +81920 float4) pfrag: B-fragments in exact MFMA operand order:
//        f16x8 index = ((nt*10 + ks)*2 + s)*64 + lane
//        value[j] = split_s(pred[q = nt*16 + (lane&15)][k = ks*32 + (lane>>4)*8 + j])
#define WS_PF 1280

// ---------------------------------------------------------------------------
__global__ void prep_scalars(const float* __restrict__ preds,
                             const float* __restrict__ tgt,
                             float* __restrict__ ws)
{
    int i = blockIdx.x*256 + threadIdx.x;            // 0..1279
    if (i < 1024) {
        const float* p = preds + i*KD;
        float s = 0.f;
        for (int k = 0; k < KD; ++k) s = fmaf(p[k], p[k], s);
        ws[i] = s;
    } else if (i < 1280) {
        const float* g = tgt + (i-1024)*KD;
        float s = 0.f;
        for (int k = 0; k < KD; ++k) s = fmaf(g[k], g[k], s);
        ws[i] = s;
    }
}

// B-fragments pre-swizzled so the main loop's B load is ONE coalesced dwordx4.
__global__ void prep_pfrag(const float* __restrict__ preds, float* __restrict__ ws)
{
    int idx = blockIdx.x*256 + threadIdx.x;          // 64nt*10ks*2s*64lane = 81920
    if (idx >= 64*KSTEPS*2*64) return;
    int lane = idx & 63;
    int r    = idx >> 6;
    int s    = r & 1;  r >>= 1;
    int ks   = r % KSTEPS;
    int nt   = r / KSTEPS;
    int q    = nt*16 + (lane & 15);
    int kb   = ks*32 + (lane >> 4)*8;
    f16x8 v;
    #pragma unroll
    for (int j = 0; j < 8; ++j) {
        int k = kb + j;
        float x = (k < KD) ? preds[q*KD + k] : 0.f;
        f16 h = (f16)x;
        v[j] = s ? (f16)(x - (float)h) : h;
    }
    ((f16x8*)(ws + WS_PF))[idx] = v;
}

// ---------------------------------------------------------------------------
// One block = one target t x all 1024 queries.  8 waves x 8 N-tiles each.
// M = 14 tiles: 0..6 fwd (a = mt*16+row, valid a<100), 7..13 bwd.
// A[a][k] = ext[300-3a+k]; f16 hi/lo in 8 byte-rotated LDS copies so every
// A-fragment read is an aligned ds_read_b128 (offset c = (340-3*col)&7 is
// ks- and mt-invariant since 48*mt and 32*ks are 0 mod 8).
// ---------------------------------------------------------------------------
__global__ __launch_bounds__(512, 2) void matcher_mfma(
    const float* __restrict__ ws,      // p2 / v2 / pfrag
    const float* __restrict__ tgt,     // [256][300]
    const float* __restrict__ plog,    // [1024][2]
    const float* __restrict__ ptyp,    // [1024][4]
    const float* __restrict__ clog,    // [1024][2]
    const int*   __restrict__ labels,  // [256]
    const int*   __restrict__ iscl,    // [256]
    const float* __restrict__ clw,     // [256]
    float* __restrict__ out)           // [2][1024][256] flat fp32
{
    __shared__ __align__(16) f16 sext[4][8][EXTLEN];  // {Fh,Fl,Rh,Rl} x 8 rot copies
    __shared__ float redD[4096];                      // [w][nt][rg*16+col]
    __shared__ int   redI[4096];
    __shared__ float sopen[2][1024];                  // d2[v=0], d2[v=100]

    const int t    = blockIdx.x;
    const int tid  = threadIdx.x;
    const int lane = tid & 63;
    const int w    = tid >> 6;          // wave 0..7 -> N-tiles w*8..w*8+7
    const int col  = lane & 15;         // q within N-tile / a-row within M-tile
    const int rg   = lane >> 4;         // row-group (C-layout) / k-group (A/B)

    // Stage ext (fwd+rev, hi+lo f16 split, 8 byte-rotated copies).
    const float* tg = tgt + t*KD;
    for (int x = tid; x < EXTLEN; x += 512) {
        int e = x - EXTOFF;
        float vF = 0.f, vR = 0.f;
        if (e >= 0 && e < 600) {
            int m = (e >= 300) ? e - 300 : e;
            vF = tg[m];
            int jj = m / 3, c3 = m - 3*jj;
            vR = tg[(NPTS-1-jj)*3 + c3];
        }
        f16 fh = (f16)vF, fl = (f16)(vF - (float)fh);
        f16 rh = (f16)vR, rl = (f16)(vR - (float)rh);
        #pragma unroll
        for (int c = 0; c < 8; ++c) {
            int y = x - c;
            if (y >= 0) {
                sext[0][c][y] = fh; sext[1][c][y] = fl;
                sext[2][c][y] = rh; sext[3][c][y] = rl;
            }
        }
    }

    const float v2t = ws[1024 + t];
    const int ntb = w*8;
    float p2v[8];
    #pragma unroll
    for (int nt = 0; nt < 8; ++nt) p2v[nt] = ws[(ntb+nt)*16 + col];

    const f16x8* __restrict__ pfrag = (const f16x8*)(ws + WS_PF);
    __syncthreads();

    float minD[8]; int minI[8];
    #pragma unroll
    for (int nt = 0; nt < 8; ++nt) { minD[nt] = 3.4028235e38f; minI[nt] = 0; }

    const int cA = (EXTOFF + 300 - 3*col) & 7;     // rotation copy, lane-fixed

    for (int mp = 0; mp < 7; ++mp) {               // M-tile pairs, ascending v
        const int mt0 = 2*mp, mt1 = mt0 + 1;
        const int mtp0 = (mt0 < 7) ? mt0 : mt0-7;
        const int mtp1 = (mt1 < 7) ? mt1 : mt1-7;
        const int sel0 = (mt0 < 7) ? 0 : 2;
        const int sel1 = (mt1 < 7) ? 0 : 2;
        const int idx0 = EXTOFF + 300 - 48*mtp0 - 3*col + 8*rg - cA;
        const int idx1 = EXTOFF + 300 - 48*mtp1 - 3*col + 8*rg - cA;

        f32x4 acc[2][8];
        #pragma unroll
        for (int h = 0; h < 2; ++h)
            #pragma unroll
            for (int nt = 0; nt < 8; ++nt) acc[h][nt] = (f32x4){0.f,0.f,0.f,0.f};

        for (int ks = 0; ks < KSTEPS; ++ks) {
            const int o = 32*ks;
            f16x8 a0h = *(const f16x8*)&sext[sel0  ][cA][idx0 + o];
            f16x8 a0l = *(const f16x8*)&sext[sel0+1][cA][idx0 + o];
            f16x8 a1h = *(const f16x8*)&sext[sel1  ][cA][idx1 + o];
            f16x8 a1l = *(const f16x8*)&sext[sel1+1][cA][idx1 + o];
            #pragma unroll
            for (int nt = 0; nt < 8; ++nt) {
                const int fi = ((ntb+nt)*KSTEPS + ks)*128 + lane;
                f16x8 bh = pfrag[fi];
                f16x8 bl = pfrag[fi + 64];
                acc[0][nt] = MFMA16(a0h, bh, acc[0][nt], 0,0,0);
                acc[0][nt] = MFMA16(a0h, bl, acc[0][nt], 0,0,0);
                acc[0][nt] = MFMA16(a0l, bh, acc[0][nt], 0,0,0);
                acc[1][nt] = MFMA16(a1h, bh, acc[1][nt], 0,0,0);
                acc[1][nt] = MFMA16(a1h, bl, acc[1][nt], 0,0,0);
                acc[1][nt] = MFMA16(a1l, bh, acc[1][nt], 0,0,0);
            }
        }

        // Fold D -> d2 -> running (min, argmin).  Ascending v within lane;
        // cross-lane ties resolved later by lexicographic (d, v).
        #pragma unroll
        for (int h = 0; h < 2; ++h) {
            const int mt   = 2*mp + h;
            const int mtp  = (mt < 7) ? mt : mt-7;
            const int voff = (mt < 7) ? 0 : 100;
            const int ab   = mtp*16 + rg*4;
            #pragma unroll
            for (int nt = 0; nt < 8; ++nt) {
                const float s2 = v2t + p2v[nt];
                #pragma unroll
                for (int r = 0; r < 4; ++r) {
                    const int al = ab + r;
                    if (al < 100) {
                        float d2 = fmaxf(fmaf(-2.f, acc[h][nt][r], s2), 0.f) * 0.01f;
                        int vlog = voff + al;
                        if (d2 < minD[nt]) { minD[nt] = d2; minI[nt] = vlog; }
                        if (al == 0) sopen[voff ? 1 : 0][(ntb+nt)*16 + col] = d2;
                    }
                }
            }
        }
    }

    #pragma unroll
    for (int nt = 0; nt < 8; ++nt) {
        redD[(w*8 + nt)*64 + lane] = minD[nt];
        redI[(w*8 + nt)*64 + lane] = minI[nt];
    }
    __syncthreads();

    // Epilogue: one thread per 2 queries.
    for (int q = tid; q < Q_TOT; q += 512) {
        const int ww  = q >> 7;
        const int ntl = (q >> 4) & 7;
        const int cc  = q & 15;
        const int base = (ww*8 + ntl)*64 + cc;
        float bd = redD[base]; int bi = redI[base];
        #pragma unroll
        for (int g = 1; g < 4; ++g) {
            float d = redD[base + g*16]; int i = redI[base + g*16];
            if (d < bd || (d == bd && i < bi)) { bd = d; bi = i; }
        }
        int mapped = (bi <= NPTS-1) ? bi : (2*NPTS-1 - bi);
        float od   = fminf(sopen[0][q], sopen[1][q]);
        int   isc  = iscl[t];
        float geom = isc ? bd : od;
        int   ido  = isc ? mapped : 0;
        geom *= clw[t];

        float t0 = ptyp[q*4+0], t1 = ptyp[q*4+1];
        float t2 = ptyp[q*4+2], t3 = ptyp[q*4+3];
        float mx = fmaxf(fmaxf(t0,t1), fmaxf(t2,t3));
        float e0 = expf(t0-mx), e1 = expf(t1-mx), e2 = expf(t2-mx), e3 = expf(t3-mx);
        float rs = 1.0f/(e0+e1+e2+e3);
        int lab  = labels[t];
        float el = (lab == 0) ? e0 : (lab == 1) ? e1 : (lab == 2) ? e2 : e3;
        float cost = -logf(el*rs + EPSV);
        float v0 = plog[q*2+0], v1 = plog[q*2+1];
        cost += -logf(1.0f/(1.0f + expf(v1-v0)) + EPSV);
        float c0 = clog[q*2+0], c1 = clog[q*2+1];
        float pc = isc ? (1.0f/(1.0f + expf(c0-c1))) : (1.0f/(1.0f + expf(c1-c0)));
        cost += -logf(pc + EPSV);

        float C = geom + cost;
        out[q*T_TOT + t]               = C;
        out[Q_TOT*T_TOT + q*T_TOT + t] = (float)ido;
    }
}

extern "C" void kernel_launch(void* const* d_in, const int* in_sizes, int n_in,
                              void* d_out, int out_size, void* d_ws, size_t ws_size,
                              hipStream_t stream)
{
    const float* preds  = (const float*)d_in[0];  // pred_curve_points (1,1024,100,3)
    const float* plog   = (const float*)d_in[1];  // pred_curve_logits (1,1024,2)
    const float* ptyp   = (const float*)d_in[2];  // pred_curve_type   (1,1024,4)
    const float* clog   = (const float*)d_in[3];  // closed_curve_logits (1,1024,2)
    const float* tgt    = (const float*)d_in[4];  // tgt_curve_points  (256,100,3)
    const int*   labels = (const int*)d_in[5];    // tgt_labels (256)
    const int*   iscl   = (const int*)d_in[6];    // tgt_is_closed (256)
    const float* clw    = (const float*)d_in[7];  // curve_length_weighting (256)
    float* out = (float*)d_out;
    float* ws  = (float*)d_ws;    // 1280 + 327680 floats = 1.32 MB

    prep_scalars<<<dim3(5),   dim3(256), 0, stream>>>(preds, tgt, ws);
    prep_pfrag  <<<dim3(320), dim3(256), 0, stream>>>(preds, ws);
    matcher_mfma<<<dim3(T_TOT), dim3(512), 0, stream>>>(
        ws, tgt, plog, ptyp, clog, labels, iscl, clw, out);
}

// Round 11
// 234.925 us; speedup vs baseline: 2.7591x; 2.2254x over previous
//
#include <hip/hip_runtime.h>
#include <hip/hip_fp16.h>

#define Q_TOT 1024
#define T_TOT 256
#define NPTS  100
#define KD    300
#define EPSV  1e-6f

#define KSTEPS 10            // 10 * 32 = 320 >= 300 (zero-padded K)
#define MT     14            // 7 M-tiles fwd (rows 0..111) + 7 bwd

typedef _Float16 f16;
typedef _Float16 f16x8 __attribute__((ext_vector_type(8)));
typedef float    f32x4 __attribute__((ext_vector_type(4)));
#define MFMA16 __builtin_amdgcn_mfma_f32_16x16x32_f16

// ws layout (floats):
//   [0,1024)        p2[q] = sum(pred_q^2)
//   [1024,1280)     v2[t] = sum(tgt_t^2)
//   [1280,+327680)  pfrag: B-fragments, f16x8 idx = ((nt*10+ks)*2+s)*64+lane
//   [WS_AF, ...)    afrag: A-fragments per target, f16x8 idx =
//                   t*17920 + ((mt*10+ks)*2+s)*64+lane   (73.4 MB)
#define WS_PF 1280
#define WS_AF (WS_PF + 81920*4)
#define AFRAG_PER_T (MT*KSTEPS*2*64)   // 17920 f16x8 per target

// ---------------------------------------------------------------------------
__global__ void prep_scalars(const float* __restrict__ preds,
                             const float* __restrict__ tgt,
                             float* __restrict__ ws)
{
    int i = blockIdx.x*256 + threadIdx.x;            // 0..1279
    if (i < 1024) {
        const float* p = preds + i*KD;
        float s = 0.f;
        for (int k = 0; k < KD; ++k) s = fmaf(p[k], p[k], s);
        ws[i] = s;
    } else if (i < 1280) {
        const float* g = tgt + (i-1024)*KD;
        float s = 0.f;
        for (int k = 0; k < KD; ++k) s = fmaf(g[k], g[k], s);
        ws[i] = s;
    }
}

// B-fragments pre-swizzled: main-loop B load is ONE coalesced dwordx4.
__global__ void prep_pfrag(const float* __restrict__ preds, float* __restrict__ ws)
{
    int idx = blockIdx.x*256 + threadIdx.x;          // 64nt*10ks*2s*64lane = 81920
    if (idx >= 64*KSTEPS*2*64) return;
    int lane = idx & 63;
    int r    = idx >> 6;
    int s    = r & 1;  r >>= 1;
    int ks   = r % KSTEPS;
    int nt   = r / KSTEPS;
    int q    = nt*16 + (lane & 15);
    int kb   = ks*32 + (lane >> 4)*8;
    f16x8 v;
    #pragma unroll
    for (int j = 0; j < 8; ++j) {
        int k = kb + j;
        float x = (k < KD) ? preds[q*KD + k] : 0.f;
        f16 h = (f16)x;
        v[j] = s ? (f16)(x - (float)h) : h;
    }
    ((f16x8*)(ws + WS_PF))[idx] = v;
}

// A-fragments pre-swizzled per target (kills R10's 2.4M LDS bank conflicts:
// hot loop reads become coalesced global dwordx4 shared by all waves via L2).
__global__ void prep_afrag(const float* __restrict__ tgt, float* __restrict__ ws)
{
    __shared__ float extF[600], extR[600];
    const int t = blockIdx.x;
    const float* tg = tgt + t*KD;
    for (int x = threadIdx.x; x < 600; x += 512) {
        int m = (x >= 300) ? x-300 : x;
        extF[x] = tg[m];
        int jj = m / 3, c3 = m - 3*jj;
        extR[x] = tg[(NPTS-1-jj)*3 + c3];
    }
    __syncthreads();
    f16x8* outp = (f16x8*)(ws + WS_AF) + t*AFRAG_PER_T;
    for (int j = threadIdx.x; j < AFRAG_PER_T; j += 512) {
        int lane = j & 63;
        int r    = j >> 6;
        int s    = r & 1;  r >>= 1;
        int ks   = r % KSTEPS;
        int mt   = r / KSTEPS;
        int col  = lane & 15;
        int rg   = lane >> 4;
        int mtp  = (mt < 7) ? mt : mt-7;
        int a    = mtp*16 + col;
        const float* ext = (mt < 7) ? extF : extR;
        f16x8 v;
        #pragma unroll
        for (int jj = 0; jj < 8; ++jj) {
            int k = ks*32 + rg*8 + jj;
            float x = (a < 100 && k < KD) ? ext[300 - 3*a + k] : 0.f;
            f16 h = (f16)x;
            v[jj] = s ? (f16)(x - (float)h) : h;
        }
        outp[j] = v;
    }
}

// ---------------------------------------------------------------------------
// One block = one target t x all 1024 queries.  8 waves x 8 N-tiles each.
// No LDS in the hot loop; A and B fragments are coalesced global loads in
// exact operand order (A shared by all waves -> L2 broadcast; B shared
// across blocks -> L2-resident).  f16 3-term split, verified absmax 0 (R10).
// ---------------------------------------------------------------------------
__global__ __launch_bounds__(512) void matcher_mfma(
    const float* __restrict__ ws,      // p2 / v2 / pfrag / afrag
    const float* __restrict__ plog,    // [1024][2]
    const float* __restrict__ ptyp,    // [1024][4]
    const float* __restrict__ clog,    // [1024][2]
    const int*   __restrict__ labels,  // [256]
    const int*   __restrict__ iscl,    // [256]
    const float* __restrict__ clw,     // [256]
    float* __restrict__ out)           // [2][1024][256] flat fp32
{
    __shared__ float redD[4096];                      // [w][nt][rg*16+col]
    __shared__ int   redI[4096];
    __shared__ float sopen[2][1024];                  // d2[v=0], d2[v=100]

    const int t    = blockIdx.x;
    const int tid  = threadIdx.x;
    const int lane = tid & 63;
    const int w    = tid >> 6;          // wave 0..7 -> N-tiles w*8..w*8+7
    const int col  = lane & 15;
    const int rg   = lane >> 4;

    const float v2t = ws[1024 + t];
    const int ntb = w*8;
    float p2v[8];
    #pragma unroll
    for (int nt = 0; nt < 8; ++nt) p2v[nt] = ws[(ntb+nt)*16 + col];

    const f16x8* __restrict__ pfrag = (const f16x8*)(ws + WS_PF);
    const f16x8* __restrict__ afrag = (const f16x8*)(ws + WS_AF) + t*AFRAG_PER_T;

    float minD[8]; int minI[8];
    #pragma unroll
    for (int nt = 0; nt < 8; ++nt) { minD[nt] = 3.4028235e38f; minI[nt] = 0; }

    for (int mp = 0; mp < 7; ++mp) {               // M-tile pairs, ascending v
        const int mt0 = 2*mp, mt1 = mt0 + 1;

        f32x4 acc[2][8];
        #pragma unroll
        for (int h = 0; h < 2; ++h)
            #pragma unroll
            for (int nt = 0; nt < 8; ++nt) acc[h][nt] = (f32x4){0.f,0.f,0.f,0.f};

        for (int ks = 0; ks < KSTEPS; ++ks) {
            const int i0 = (mt0*KSTEPS + ks)*128 + lane;
            const int i1 = (mt1*KSTEPS + ks)*128 + lane;
            f16x8 a0h = afrag[i0];
            f16x8 a0l = afrag[i0 + 64];
            f16x8 a1h = afrag[i1];
            f16x8 a1l = afrag[i1 + 64];
            #pragma unroll
            for (int nt = 0; nt < 8; ++nt) {
                const int fi = ((ntb+nt)*KSTEPS + ks)*128 + lane;
                f16x8 bh = pfrag[fi];
                f16x8 bl = pfrag[fi + 64];
                acc[0][nt] = MFMA16(a0h, bh, acc[0][nt], 0,0,0);
                acc[0][nt] = MFMA16(a0h, bl, acc[0][nt], 0,0,0);
                acc[0][nt] = MFMA16(a0l, bh, acc[0][nt], 0,0,0);
                acc[1][nt] = MFMA16(a1h, bh, acc[1][nt], 0,0,0);
                acc[1][nt] = MFMA16(a1h, bl, acc[1][nt], 0,0,0);
                acc[1][nt] = MFMA16(a1l, bh, acc[1][nt], 0,0,0);
            }
        }

        // Fold D -> d2 -> running (min, argmin); identical to R10 (verified).
        #pragma unroll
        for (int h = 0; h < 2; ++h) {
            const int mt   = 2*mp + h;
            const int mtp  = (mt < 7) ? mt : mt-7;
            const int voff = (mt < 7) ? 0 : 100;
            const int ab   = mtp*16 + rg*4;
            #pragma unroll
            for (int nt = 0; nt < 8; ++nt) {
                const float s2 = v2t + p2v[nt];
                #pragma unroll
                for (int r = 0; r < 4; ++r) {
                    const int al = ab + r;
                    if (al < 100) {
                        float d2 = fmaxf(fmaf(-2.f, acc[h][nt][r], s2), 0.f) * 0.01f;
                        int vlog = voff + al;
                        if (d2 < minD[nt]) { minD[nt] = d2; minI[nt] = vlog; }
                        if (al == 0) sopen[voff ? 1 : 0][(ntb+nt)*16 + col] = d2;
                    }
                }
            }
        }
    }

    #pragma unroll
    for (int nt = 0; nt < 8; ++nt) {
        redD[(w*8 + nt)*64 + lane] = minD[nt];
        redI[(w*8 + nt)*64 + lane] = minI[nt];
    }
    __syncthreads();

    // Epilogue: cross-row-group reduce (lexicographic (d,v) = first occurrence),
    // then cost-class terms; 2 queries per thread.
    for (int q = tid; q < Q_TOT; q += 512) {
        const int ww  = q >> 7;
        const int ntl = (q >> 4) & 7;
        const int cc  = q & 15;
        const int base = (ww*8 + ntl)*64 + cc;
        float bd = redD[base]; int bi = redI[base];
        #pragma unroll
        for (int g = 1; g < 4; ++g) {
            float d = redD[base + g*16]; int i = redI[base + g*16];
            if (d < bd || (d == bd && i < bi)) { bd = d; bi = i; }
        }
        int mapped = (bi <= NPTS-1) ? bi : (2*NPTS-1 - bi);
        float od   = fminf(sopen[0][q], sopen[1][q]);
        int   isc  = iscl[t];
        float geom = isc ? bd : od;
        int   ido  = isc ? mapped : 0;
        geom *= clw[t];

        float t0 = ptyp[q*4+0], t1 = ptyp[q*4+1];
        float t2 = ptyp[q*4+2], t3 = ptyp[q*4+3];
        float mx = fmaxf(fmaxf(t0,t1), fmaxf(t2,t3));
        float e0 = expf(t0-mx), e1 = expf(t1-mx), e2 = expf(t2-mx), e3 = expf(t3-mx);
        float rs = 1.0f/(e0+e1+e2+e3);
        int lab  = labels[t];
        float el = (lab == 0) ? e0 : (lab == 1) ? e1 : (lab == 2) ? e2 : e3;
        float cost = -logf(el*rs + EPSV);
        float v0 = plog[q*2+0], v1 = plog[q*2+1];
        cost += -logf(1.0f/(1.0f + expf(v1-v0)) + EPSV);
        float c0 = clog[q*2+0], c1 = clog[q*2+1];
        float pc = isc ? (1.0f/(1.0f + expf(c0-c1))) : (1.0f/(1.0f + expf(c1-c0)));
        cost += -logf(pc + EPSV);

        float C = geom + cost;
        out[q*T_TOT + t]               = C;
        out[Q_TOT*T_TOT + q*T_TOT + t] = (float)ido;
    }
}

extern "C" void kernel_launch(void* const* d_in, const int* in_sizes, int n_in,
                              void* d_out, int out_size, void* d_ws, size_t ws_size,
                              hipStream_t stream)
{
    const float* preds  = (const float*)d_in[0];  // pred_curve_points (1,1024,100,3)
    const float* plog   = (const float*)d_in[1];  // pred_curve_logits (1,1024,2)
    const float* ptyp   = (const float*)d_in[2];  // pred_curve_type   (1,1024,4)
    const float* clog   = (const float*)d_in[3];  // closed_curve_logits (1,1024,2)
    const float* tgt    = (const float*)d_in[4];  // tgt_curve_points  (256,100,3)
    const int*   labels = (const int*)d_in[5];    // tgt_labels (256)
    const int*   iscl   = (const int*)d_in[6];    // tgt_is_closed (256)
    const float* clw    = (const float*)d_in[7];  // curve_length_weighting (256)
    float* out = (float*)d_out;
    float* ws  = (float*)d_ws;    // needs WS_AF*4 + 73.4 MB ≈ 74.7 MB

    prep_scalars<<<dim3(5),     dim3(256), 0, stream>>>(preds, tgt, ws);
    prep_pfrag  <<<dim3(320),   dim3(256), 0, stream>>>(preds, ws);
    prep_afrag  <<<dim3(T_TOT), dim3(512), 0, stream>>>(tgt, ws);
    matcher_mfma<<<dim3(T_TOT), dim3(512), 0, stream>>>(
        ws, plog, ptyp, clog, labels, iscl, clw, out);
}

// Round 12
// 223.930 us; speedup vs baseline: 2.8946x; 1.0491x over previous
//
#include <hip/hip_runtime.h>
#include <hip/hip_fp16.h>

#define Q_TOT 1024
#define T_TOT 256
#define NPTS  100
#define KD    300
#define EPSV  1e-6f

#define KSTEPS 10            // 10 * 32 = 320 >= 300 (zero-padded K)
#define MT     14            // 7 M-tiles fwd (rows 0..111) + 7 bwd

typedef _Float16 f16;
typedef _Float16 f16x8 __attribute__((ext_vector_type(8)));
typedef float    f32x4 __attribute__((ext_vector_type(4)));
#define MFMA16 __builtin_amdgcn_mfma_f32_16x16x32_f16

// ws layout (floats):
//   [0,1024)        p2[q] = sum(pred_q^2)
//   [1024,1280)     v2[t] = sum(tgt_t^2)
//   [1280,+327680)  pfrag: B-fragments, f16x8 idx = ((nt*10+ks)*2+s)*64+lane
//   [WS_AF, ...)    afrag: A-fragments per target, f16x8 idx =
//                   t*17920 + ((mt*10+ks)*2+s)*64+lane   (73.4 MB)
#define WS_PF 1280
#define WS_AF (WS_PF + 81920*4)
#define AFRAG_PER_T (MT*KSTEPS*2*64)   // 17920 f16x8 per target

// ---------------------------------------------------------------------------
__global__ void prep_scalars(const float* __restrict__ preds,
                             const float* __restrict__ tgt,
                             float* __restrict__ ws)
{
    int i = blockIdx.x*256 + threadIdx.x;            // 0..1279
    if (i < 1024) {
        const float* p = preds + i*KD;
        float s = 0.f;
        for (int k = 0; k < KD; ++k) s = fmaf(p[k], p[k], s);
        ws[i] = s;
    } else if (i < 1280) {
        const float* g = tgt + (i-1024)*KD;
        float s = 0.f;
        for (int k = 0; k < KD; ++k) s = fmaf(g[k], g[k], s);
        ws[i] = s;
    }
}

// B-fragments pre-swizzled: main-loop B load is ONE coalesced dwordx4.
__global__ void prep_pfrag(const float* __restrict__ preds, float* __restrict__ ws)
{
    int idx = blockIdx.x*256 + threadIdx.x;          // 64nt*10ks*2s*64lane = 81920
    if (idx >= 64*KSTEPS*2*64) return;
    int lane = idx & 63;
    int r    = idx >> 6;
    int s    = r & 1;  r >>= 1;
    int ks   = r % KSTEPS;
    int nt   = r / KSTEPS;
    int q    = nt*16 + (lane & 15);
    int kb   = ks*32 + (lane >> 4)*8;
    f16x8 v;
    #pragma unroll
    for (int j = 0; j < 8; ++j) {
        int k = kb + j;
        float x = (k < KD) ? preds[q*KD + k] : 0.f;
        f16 h = (f16)x;
        v[j] = s ? (f16)(x - (float)h) : h;
    }
    ((f16x8*)(ws + WS_PF))[idx] = v;
}

// A-fragments pre-swizzled per target (coalesced global loads in the hot loop,
// shared by all waves via L2 -- killed R10's LDS bank conflicts).
__global__ void prep_afrag(const float* __restrict__ tgt, float* __restrict__ ws)
{
    __shared__ float extF[600], extR[600];
    const int t = blockIdx.x;
    const float* tg = tgt + t*KD;
    for (int x = threadIdx.x; x < 600; x += 512) {
        int m = (x >= 300) ? x-300 : x;
        extF[x] = tg[m];
        int jj = m / 3, c3 = m - 3*jj;
        extR[x] = tg[(NPTS-1-jj)*3 + c3];
    }
    __syncthreads();
    f16x8* outp = (f16x8*)(ws + WS_AF) + t*AFRAG_PER_T;
    for (int j = threadIdx.x; j < AFRAG_PER_T; j += 512) {
        int lane = j & 63;
        int r    = j >> 6;
        int s    = r & 1;  r >>= 1;
        int ks   = r % KSTEPS;
        int mt   = r / KSTEPS;
        int col  = lane & 15;
        int rg   = lane >> 4;
        int mtp  = (mt < 7) ? mt : mt-7;
        int a    = mtp*16 + col;
        const float* ext = (mt < 7) ? extF : extR;
        f16x8 v;
        #pragma unroll
        for (int jj = 0; jj < 8; ++jj) {
            int k = ks*32 + rg*8 + jj;
            float x = (a < 100 && k < KD) ? ext[300 - 3*a + k] : 0.f;
            f16 h = (f16)x;
            v[jj] = s ? (f16)(x - (float)h) : h;
        }
        outp[j] = v;
    }
}

// ---------------------------------------------------------------------------
// One sweep: NMT M-tiles x 8 N-tiles, K=320.  acc[NMT][8] stays in registers;
// B is re-read once per sweep (the L2 traffic driver: 4 sweeps vs R11's 7).
// Accumulation order per acc chain identical to R11 (verified absmax 0).
// ---------------------------------------------------------------------------
template<int MTB, int NMT>
__device__ __forceinline__ void sweep(const f16x8* __restrict__ afrag,
                                      const f16x8* __restrict__ pfrag,
                                      int ntb, int lane, int col, int rg,
                                      float v2t, const float (&p2v)[8],
                                      float (&minD)[8], int (&minI)[8],
                                      float (*sopen)[1024])
{
    f32x4 acc[NMT][8];
    #pragma unroll
    for (int h = 0; h < NMT; ++h)
        #pragma unroll
        for (int nt = 0; nt < 8; ++nt) acc[h][nt] = (f32x4){0.f,0.f,0.f,0.f};

    for (int ks = 0; ks < KSTEPS; ++ks) {
        f16x8 ah[NMT], alo[NMT];
        #pragma unroll
        for (int h = 0; h < NMT; ++h) {
            const int i = ((MTB+h)*KSTEPS + ks)*128 + lane;
            ah[h]  = afrag[i];
            alo[h] = afrag[i + 64];
        }
        #pragma unroll
        for (int nt = 0; nt < 8; ++nt) {
            const int fi = ((ntb+nt)*KSTEPS + ks)*128 + lane;
            f16x8 bh = pfrag[fi];
            f16x8 bl = pfrag[fi + 64];
            #pragma unroll
            for (int h = 0; h < NMT; ++h) {
                acc[h][nt] = MFMA16(ah[h],  bh, acc[h][nt], 0,0,0);
                acc[h][nt] = MFMA16(ah[h],  bl, acc[h][nt], 0,0,0);
                acc[h][nt] = MFMA16(alo[h], bh, acc[h][nt], 0,0,0);
            }
        }
    }

    // Fold D -> d2 -> running (min, argmin), ascending v within lane.
    #pragma unroll
    for (int h = 0; h < NMT; ++h) {
        const int mt   = MTB + h;
        const int mtp  = (mt < 7) ? mt : mt-7;
        const int voff = (mt < 7) ? 0 : 100;
        const int ab   = mtp*16 + rg*4;
        #pragma unroll
        for (int nt = 0; nt < 8; ++nt) {
            const float s2 = v2t + p2v[nt];
            #pragma unroll
            for (int r = 0; r < 4; ++r) {
                const int al = ab + r;
                if (al < 100) {
                    float d2 = fmaxf(fmaf(-2.f, acc[h][nt][r], s2), 0.f) * 0.01f;
                    int vlog = voff + al;
                    if (d2 < minD[nt]) { minD[nt] = d2; minI[nt] = vlog; }
                    if (al == 0) sopen[voff ? 1 : 0][(ntb+nt)*16 + col] = d2;
                }
            }
        }
    }
}

// ---------------------------------------------------------------------------
// One block = one target t x all 1024 queries.  8 waves x 8 N-tiles each.
// 4 M-sweeps {0-3}{4-7}{8-11}{12,13} -> B L2 traffic 2.3 -> 1.31 GB vs R11.
// ---------------------------------------------------------------------------
__global__ __launch_bounds__(512) void matcher_mfma(
    const float* __restrict__ ws,      // p2 / v2 / pfrag / afrag
    const float* __restrict__ plog,    // [1024][2]
    const float* __restrict__ ptyp,    // [1024][4]
    const float* __restrict__ clog,    // [1024][2]
    const int*   __restrict__ labels,  // [256]
    const int*   __restrict__ iscl,    // [256]
    const float* __restrict__ clw,     // [256]
    float* __restrict__ out)           // [2][1024][256] flat fp32
{
    __shared__ float redD[4096];                      // [w][nt][rg*16+col]
    __shared__ int   redI[4096];
    __shared__ float sopen[2][1024];                  // d2[v=0], d2[v=100]

    const int t    = blockIdx.x;
    const int tid  = threadIdx.x;
    const int lane = tid & 63;
    const int w    = tid >> 6;          // wave 0..7 -> N-tiles w*8..w*8+7
    const int col  = lane & 15;
    const int rg   = lane >> 4;

    const float v2t = ws[1024 + t];
    const int ntb = w*8;
    float p2v[8];
    #pragma unroll
    for (int nt = 0; nt < 8; ++nt) p2v[nt] = ws[(ntb+nt)*16 + col];

    const f16x8* __restrict__ pfrag = (const f16x8*)(ws + WS_PF);
    const f16x8* __restrict__ afrag = (const f16x8*)(ws + WS_AF) + t*AFRAG_PER_T;

    float minD[8]; int minI[8];
    #pragma unroll
    for (int nt = 0; nt < 8; ++nt) { minD[nt] = 3.4028235e38f; minI[nt] = 0; }

    sweep< 0,4>(afrag, pfrag, ntb, lane, col, rg, v2t, p2v, minD, minI, sopen);
    sweep< 4,4>(afrag, pfrag, ntb, lane, col, rg, v2t, p2v, minD, minI, sopen);
    sweep< 8,4>(afrag, pfrag, ntb, lane, col, rg, v2t, p2v, minD, minI, sopen);
    sweep<12,2>(afrag, pfrag, ntb, lane, col, rg, v2t, p2v, minD, minI, sopen);

    #pragma unroll
    for (int nt = 0; nt < 8; ++nt) {
        redD[(w*8 + nt)*64 + lane] = minD[nt];
        redI[(w*8 + nt)*64 + lane] = minI[nt];
    }
    __syncthreads();

    // Epilogue: cross-row-group reduce (lexicographic (d,v) = first occurrence),
    // then cost-class terms; 2 queries per thread.
    for (int q = tid; q < Q_TOT; q += 512) {
        const int ww  = q >> 7;
        const int ntl = (q >> 4) & 7;
        const int cc  = q & 15;
        const int base = (ww*8 + ntl)*64 + cc;
        float bd = redD[base]; int bi = redI[base];
        #pragma unroll
        for (int g = 1; g < 4; ++g) {
            float d = redD[base + g*16]; int i = redI[base + g*16];
            if (d < bd || (d == bd && i < bi)) { bd = d; bi = i; }
        }
        int mapped = (bi <= NPTS-1) ? bi : (2*NPTS-1 - bi);
        float od   = fminf(sopen[0][q], sopen[1][q]);
        int   isc  = iscl[t];
        float geom = isc ? bd : od;
        int   ido  = isc ? mapped : 0;
        geom *= clw[t];

        float t0 = ptyp[q*4+0], t1 = ptyp[q*4+1];
        float t2 = ptyp[q*4+2], t3 = ptyp[q*4+3];
        float mx = fmaxf(fmaxf(t0,t1), fmaxf(t2,t3));
        float e0 = expf(t0-mx), e1 = expf(t1-mx), e2 = expf(t2-mx), e3 = expf(t3-mx);
        float rs = 1.0f/(e0+e1+e2+e3);
        int lab  = labels[t];
        float el = (lab == 0) ? e0 : (lab == 1) ? e1 : (lab == 2) ? e2 : e3;
        float cost = -logf(el*rs + EPSV);
        float v0 = plog[q*2+0], v1 = plog[q*2+1];
        cost += -logf(1.0f/(1.0f + expf(v1-v0)) + EPSV);
        float c0 = clog[q*2+0], c1 = clog[q*2+1];
        float pc = isc ? (1.0f/(1.0f + expf(c0-c1))) : (1.0f/(1.0f + expf(c1-c0)));
        cost += -logf(pc + EPSV);

        float C = geom + cost;
        out[q*T_TOT + t]               = C;
        out[Q_TOT*T_TOT + q*T_TOT + t] = (float)ido;
    }
}

extern "C" void kernel_launch(void* const* d_in, const int* in_sizes, int n_in,
                              void* d_out, int out_size, void* d_ws, size_t ws_size,
                              hipStream_t stream)
{
    const float* preds  = (const float*)d_in[0];  // pred_curve_points (1,1024,100,3)
    const float* plog   = (const float*)d_in[1];  // pred_curve_logits (1,1024,2)
    const float* ptyp   = (const float*)d_in[2];  // pred_curve_type   (1,1024,4)
    const float* clog   = (const float*)d_in[3];  // closed_curve_logits (1,1024,2)
    const float* tgt    = (const float*)d_in[4];  // tgt_curve_points  (256,100,3)
    const int*   labels = (const int*)d_in[5];    // tgt_labels (256)
    const int*   iscl   = (const int*)d_in[6];    // tgt_is_closed (256)
    const float* clw    = (const float*)d_in[7];  // curve_length_weighting (256)
    float* out = (float*)d_out;
    float* ws  = (float*)d_ws;    // needs ≈ 74.7 MB

    prep_scalars<<<dim3(5),     dim3(256), 0, stream>>>(preds, tgt, ws);
    prep_pfrag  <<<dim3(320),   dim3(256), 0, stream>>>(preds, ws);
    prep_afrag  <<<dim3(T_TOT), dim3(512), 0, stream>>>(tgt, ws);
    matcher_mfma<<<dim3(T_TOT), dim3(512), 0, stream>>>(
        ws, plog, ptyp, clog, labels, iscl, clw, out);
}

// Round 13
// 212.725 us; speedup vs baseline: 3.0471x; 1.0527x over previous
//
#include <hip/hip_runtime.h>
#include <hip/hip_fp16.h>

#define Q_TOT 1024
#define T_TOT 256
#define NPTS  100
#define KD    300
#define EPSV  1e-6f

#define KSTEPS 10            // 10 * 32 = 320 >= 300 (zero-padded K)
#define MT     14            // 7 M-tiles fwd (rows 0..111) + 7 bwd

typedef _Float16 f16;
typedef _Float16 f16x8 __attribute__((ext_vector_type(8)));
typedef float    f32x4 __attribute__((ext_vector_type(4)));
#define MFMA16 __builtin_amdgcn_mfma_f32_16x16x32_f16

// ws layout (floats):
//   [0,1024)        p2[q] = sum(pred_q^2)
//   [1024,1280)     v2[t] = sum(tgt_t^2)
//   [1280,+327680)  pfrag: B-fragments, f16x8 idx = ((nt*10+ks)*2+s)*64+lane
//   [WS_AF, ...)    afrag: per-target A-fragments, f16x8 idx =
//                   t*17920 + ((mt*10+ks)*2+s)*64+lane   (73.4 MB)
#define WS_PF 1280
#define WS_AF (WS_PF + 81920*4)
#define AFRAG_PER_T (MT*KSTEPS*2*64)   // 17920 f16x8 per target

// ---------------------------------------------------------------------------
// Fused prep: one block per target.  Computes (a) this target's A-fragments,
// (b) a 320-f16x8 slice of pfrag, (c) p2 rows 4t..4t+3 and v2[t] with the
// EXACT sequential fmaf order of the old prep_scalars (bit-identical).
// Replaces 3 dispatches (89 us, one of which ran on 5 blocks) with 1.
// ---------------------------------------------------------------------------
__global__ __launch_bounds__(512) void prep_all(const float* __restrict__ preds,
                                                const float* __restrict__ tgt,
                                                float* __restrict__ ws)
{
    __shared__ float extF[600], extR[600];
    const int t   = blockIdx.x;
    const int tid = threadIdx.x;
    const float* tg = tgt + t*KD;

    // (b) pfrag slice: 81920 total / 256 blocks = 320 per block
    if (tid < 320) {
        int idx  = t*320 + tid;
        int lane = idx & 63;
        int r    = idx >> 6;
        int s    = r & 1;  r >>= 1;
        int ks   = r % KSTEPS;
        int nt   = r / KSTEPS;
        int q    = nt*16 + (lane & 15);
        int kb   = ks*32 + (lane >> 4)*8;
        f16x8 v;
        #pragma unroll
        for (int j = 0; j < 8; ++j) {
            int k = kb + j;
            float x = (k < KD) ? preds[q*KD + k] : 0.f;
            f16 h = (f16)x;
            v[j] = s ? (f16)(x - (float)h) : h;
        }
        ((f16x8*)(ws + WS_PF))[idx] = v;
    }

    // (c) scalars -- same sequential order as R12's prep_scalars
    if (tid >= 448 && tid < 452) {
        int q = t*4 + (tid - 448);
        const float* p = preds + q*KD;
        float s = 0.f;
        for (int k = 0; k < KD; ++k) s = fmaf(p[k], p[k], s);
        ws[q] = s;
    }
    if (tid == 452) {
        float s = 0.f;
        for (int k = 0; k < KD; ++k) s = fmaf(tg[k], tg[k], s);
        ws[1024 + t] = s;
    }

    // ext staging for afrag
    for (int x = tid; x < 600; x += 512) {
        int m = (x >= 300) ? x-300 : x;
        extF[x] = tg[m];
        int jj = m / 3, c3 = m - 3*jj;
        extR[x] = tg[(NPTS-1-jj)*3 + c3];
    }
    __syncthreads();

    // (a) A-fragments in exact MFMA operand order
    f16x8* outp = (f16x8*)(ws + WS_AF) + t*AFRAG_PER_T;
    for (int j = tid; j < AFRAG_PER_T; j += 512) {
        int lane = j & 63;
        int r    = j >> 6;
        int s    = r & 1;  r >>= 1;
        int ks   = r % KSTEPS;
        int mt   = r / KSTEPS;
        int col  = lane & 15;
        int rg   = lane >> 4;
        int mtp  = (mt < 7) ? mt : mt-7;
        int a    = mtp*16 + col;
        const float* ext = (mt < 7) ? extF : extR;
        f16x8 v;
        #pragma unroll
        for (int jj = 0; jj < 8; ++jj) {
            int k = ks*32 + rg*8 + jj;
            float x = (a < 100 && k < KD) ? ext[300 - 3*a + k] : 0.f;
            f16 h = (f16)x;
            v[jj] = s ? (f16)(x - (float)h) : h;
        }
        outp[j] = v;
    }
}

// ---------------------------------------------------------------------------
// One sweep: NMT M-tiles x 8 N-tiles, K=320.  acc[NMT][8] in registers;
// B re-read once per sweep.  Accumulation order identical to R12 (absmax 0).
// ---------------------------------------------------------------------------
template<int MTB, int NMT>
__device__ __forceinline__ void sweep(const f16x8* __restrict__ afrag,
                                      const f16x8* __restrict__ pfrag,
                                      int ntb, int lane, int col, int rg,
                                      float v2t, const float (&p2v)[8],
                                      float (&minD)[8], int (&minI)[8],
                                      float (*sopen)[1024])
{
    f32x4 acc[NMT][8];
    #pragma unroll
    for (int h = 0; h < NMT; ++h)
        #pragma unroll
        for (int nt = 0; nt < 8; ++nt) acc[h][nt] = (f32x4){0.f,0.f,0.f,0.f};

    for (int ks = 0; ks < KSTEPS; ++ks) {
        f16x8 ah[NMT], alo[NMT];
        #pragma unroll
        for (int h = 0; h < NMT; ++h) {
            const int i = ((MTB+h)*KSTEPS + ks)*128 + lane;
            ah[h]  = afrag[i];
            alo[h] = afrag[i + 64];
        }
        #pragma unroll
        for (int nt = 0; nt < 8; ++nt) {
            const int fi = ((ntb+nt)*KSTEPS + ks)*128 + lane;
            f16x8 bh = pfrag[fi];
            f16x8 bl = pfrag[fi + 64];
            #pragma unroll
            for (int h = 0; h < NMT; ++h) {
                acc[h][nt] = MFMA16(ah[h],  bh, acc[h][nt], 0,0,0);
                acc[h][nt] = MFMA16(ah[h],  bl, acc[h][nt], 0,0,0);
                acc[h][nt] = MFMA16(alo[h], bh, acc[h][nt], 0,0,0);
            }
        }
    }

    #pragma unroll
    for (int h = 0; h < NMT; ++h) {
        const int mt   = MTB + h;
        const int mtp  = (mt < 7) ? mt : mt-7;
        const int voff = (mt < 7) ? 0 : 100;
        const int ab   = mtp*16 + rg*4;
        #pragma unroll
        for (int nt = 0; nt < 8; ++nt) {
            const float s2 = v2t + p2v[nt];
            #pragma unroll
            for (int r = 0; r < 4; ++r) {
                const int al = ab + r;
                if (al < 100) {
                    float d2 = fmaxf(fmaf(-2.f, acc[h][nt][r], s2), 0.f) * 0.01f;
                    int vlog = voff + al;
                    if (d2 < minD[nt]) { minD[nt] = d2; minI[nt] = vlog; }
                    if (al == 0) sopen[voff ? 1 : 0][(ntb+nt)*16 + col] = d2;
                }
            }
        }
    }
}

// ---------------------------------------------------------------------------
// One block = one target t x all 1024 queries.  8 waves x 8 N-tiles each.
// launch_bounds(512,1): unlock the 256-VGPR tier (R12's 128 cap spilled 47MB).
// ---------------------------------------------------------------------------
__global__ __launch_bounds__(512, 1) void matcher_mfma(
    const float* __restrict__ ws,      // p2 / v2 / pfrag / afrag
    const float* __restrict__ plog,    // [1024][2]
    const float* __restrict__ ptyp,    // [1024][4]
    const float* __restrict__ clog,    // [1024][2]
    const int*   __restrict__ labels,  // [256]
    const int*   __restrict__ iscl,    // [256]
    const float* __restrict__ clw,     // [256]
    float* __restrict__ out)           // [2][1024][256] flat fp32
{
    __shared__ float redD[4096];                      // [w][nt][rg*16+col]
    __shared__ int   redI[4096];
    __shared__ float sopen[2][1024];                  // d2[v=0], d2[v=100]

    const int t    = blockIdx.x;
    const int tid  = threadIdx.x;
    const int lane = tid & 63;
    const int w    = tid >> 6;          // wave 0..7 -> N-tiles w*8..w*8+7
    const int col  = lane & 15;
    const int rg   = lane >> 4;

    const float v2t = ws[1024 + t];
    const int ntb = w*8;
    float p2v[8];
    #pragma unroll
    for (int nt = 0; nt < 8; ++nt) p2v[nt] = ws[(ntb+nt)*16 + col];

    const f16x8* __restrict__ pfrag = (const f16x8*)(ws + WS_PF);
    const f16x8* __restrict__ afrag = (const f16x8*)(ws + WS_AF) + t*AFRAG_PER_T;

    float minD[8]; int minI[8];
    #pragma unroll
    for (int nt = 0; nt < 8; ++nt) { minD[nt] = 3.4028235e38f; minI[nt] = 0; }

    sweep< 0,4>(afrag, pfrag, ntb, lane, col, rg, v2t, p2v, minD, minI, sopen);
    sweep< 4,4>(afrag, pfrag, ntb, lane, col, rg, v2t, p2v, minD, minI, sopen);
    sweep< 8,4>(afrag, pfrag, ntb, lane, col, rg, v2t, p2v, minD, minI, sopen);
    sweep<12,2>(afrag, pfrag, ntb, lane, col, rg, v2t, p2v, minD, minI, sopen);

    #pragma unroll
    for (int nt = 0; nt < 8; ++nt) {
        redD[(w*8 + nt)*64 + lane] = minD[nt];
        redI[(w*8 + nt)*64 + lane] = minI[nt];
    }
    __syncthreads();

    // Epilogue: cross-row-group reduce (lexicographic (d,v) = first occurrence),
    // then cost-class terms; 2 queries per thread.
    for (int q = tid; q < Q_TOT; q += 512) {
        const int ww  = q >> 7;
        const int ntl = (q >> 4) & 7;
        const int cc  = q & 15;
        const int base = (ww*8 + ntl)*64 + cc;
        float bd = redD[base]; int bi = redI[base];
        #pragma unroll
        for (int g = 1; g < 4; ++g) {
            float d = redD[base + g*16]; int i = redI[base + g*16];
            if (d < bd || (d == bd && i < bi)) { bd = d; bi = i; }
        }
        int mapped = (bi <= NPTS-1) ? bi : (2*NPTS-1 - bi);
        float od   = fminf(sopen[0][q], sopen[1][q]);
        int   isc  = iscl[t];
        float geom = isc ? bd : od;
        int   ido  = isc ? mapped : 0;
        geom *= clw[t];

        float t0 = ptyp[q*4+0], t1 = ptyp[q*4+1];
        float t2 = ptyp[q*4+2], t3 = ptyp[q*4+3];
        float mx = fmaxf(fmaxf(t0,t1), fmaxf(t2,t3));
        float e0 = expf(t0-mx), e1 = expf(t1-mx), e2 = expf(t2-mx), e3 = expf(t3-mx);
        float rs = 1.0f/(e0+e1+e2+e3);
        int lab  = labels[t];
        float el = (lab == 0) ? e0 : (lab == 1) ? e1 : (lab == 2) ? e2 : e3;
        float cost = -logf(el*rs + EPSV);
        float v0 = plog[q*2+0], v1 = plog[q*2+1];
        cost += -logf(1.0f/(1.0f + expf(v1-v0)) + EPSV);
        float c0 = clog[q*2+0], c1 = clog[q*2+1];
        float pc = isc ? (1.0f/(1.0f + expf(c0-c1))) : (1.0f/(1.0f + expf(c1-c0)));
        cost += -logf(pc + EPSV);

        float C = geom + cost;
        out[q*T_TOT + t]               = C;
        out[Q_TOT*T_TOT + q*T_TOT + t] = (float)ido;
    }
}

extern "C" void kernel_launch(void* const* d_in, const int* in_sizes, int n_in,
                              void* d_out, int out_size, void* d_ws, size_t ws_size,
                              hipStream_t stream)
{
    const float* preds  = (const float*)d_in[0];  // pred_curve_points (1,1024,100,3)
    const float* plog   = (const float*)d_in[1];  // pred_curve_logits (1,1024,2)
    const float* ptyp   = (const float*)d_in[2];  // pred_curve_type   (1,1024,4)
    const float* clog   = (const float*)d_in[3];  // closed_curve_logits (1,1024,2)
    const float* tgt    = (const float*)d_in[4];  // tgt_curve_points  (256,100,3)
    const int*   labels = (const int*)d_in[5];    // tgt_labels (256)
    const int*   iscl   = (const int*)d_in[6];    // tgt_is_closed (256)
    const float* clw    = (const float*)d_in[7];  // curve_length_weighting (256)
    float* out = (float*)d_out;
    float* ws  = (float*)d_ws;    // needs ≈ 74.7 MB

    prep_all    <<<dim3(T_TOT), dim3(512), 0, stream>>>(preds, tgt, ws);
    matcher_mfma<<<dim3(T_TOT), dim3(512), 0, stream>>>(
        ws, plog, ptyp, clog, labels, iscl, clw, out);
}